// Round 2
// baseline (50409.250 us; speedup 1.0000x reference)
//
#include <hip/hip_runtime.h>
#include <cmath>

#define NCU     256
#define TPB     512      // 8 waves
#define HID     2048
#define EMBD    512
#define HIN     2560
#define TSTEPS  4096
#define NCH     256

__device__ __forceinline__ float sig_(float x) { return 1.f / (1.f + __expf(-x)); }
__device__ __forceinline__ float th_(float x)  { float e = __expf(2.f * x); return 1.f - 2.f / (e + 1.f); }

extern "C" __global__ void __launch_bounds__(TPB, 2)
lstm_persist(const int* __restrict__ seq,
             const float* __restrict__ emb,
             const float* __restrict__ Wf, const float* __restrict__ bf,
             const float* __restrict__ Wi, const float* __restrict__ bi,
             const float* __restrict__ Wo, const float* __restrict__ bo,
             const float* __restrict__ Wc, const float* __restrict__ bc,
             const float* __restrict__ Wout, const float* __restrict__ bout,
             float* __restrict__ dout,
             unsigned* __restrict__ cnt,     // [0]=global, [64+64g]=group g
             float* __restrict__ hbuf)       // [2][2048] ping-pong
{
    const int b    = blockIdx.x;          // CU id == output char id
    const int tid  = threadIdx.x;
    const int wave = tid >> 6;
    const int lane = tid & 63;
    const int hidx = b * 8 + wave;        // h index owned by this wave

    __shared__ float hs[HID];
    __shared__ float wpart[8];

    // ---- persistent weights in registers ----
    float wh[4][32];   // recurrent part: col = EMBD + lane + 64*q  (coalesced loads)
    float wx[4][8];    // input part:     col = lane + 64*j
    {
        const float* Wm[4] = { Wf, Wi, Wo, Wc };
        #pragma unroll
        for (int g = 0; g < 4; ++g) {
            const float* row = Wm[g] + (size_t)hidx * HIN;
            #pragma unroll
            for (int q = 0; q < 32; ++q) wh[g][q] = row[EMBD + lane + 64 * q];
            #pragma unroll
            for (int j = 0; j < 8; ++j)  wx[g][j] = row[lane + 64 * j];
        }
    }
    const float bias0 = bf[hidx], bias1 = bi[hidx], bias2 = bo[hidx], bias3 = bc[hidx];
    float wrow[4];     // Wout row b, cols tid + 512*k
    #pragma unroll
    for (int k = 0; k < 4; ++k) wrow[k] = Wout[(size_t)b * HID + tid + 512 * k];
    const float boutb = bout[b];

    unsigned* gcnt = cnt;
    unsigned* xcnt = cnt + 64 + 64 * (b >> 5);   // 8 groups of 32 blocks

    float c = 0.f;
    int ch = seq[0];

    for (int t = 0; t <= TSTEPS; ++t) {
        // prefetch x for this step (independent of h, overlaps the spin)
        float xv[8];
        if (t < TSTEPS) {
            const float* erow = emb + (size_t)ch * EMBD;
            #pragma unroll
            for (int j = 0; j < 8; ++j) xv[j] = erow[lane + 64 * j];
        }
        int ch_next = (t + 1 < TSTEPS) ? seq[t + 1] : 0;

        // ---- wait for h_t ----
        if (t > 0) {
            if (tid == 0) {
                const unsigned need = 8u * (unsigned)t;
                while (__hip_atomic_load(gcnt, __ATOMIC_ACQUIRE, __HIP_MEMORY_SCOPE_AGENT) < need)
                    __builtin_amdgcn_s_sleep(1);
            }
            __syncthreads();                                  // BAR A
            // write out[t-2] (partials computed at end of iteration t-1, synced by BAR A)
            if (tid == 0 && t >= 2) {
                float s = wpart[0] + wpart[1] + wpart[2] + wpart[3]
                        + wpart[4] + wpart[5] + wpart[6] + wpart[7];
                dout[(size_t)(t - 2) * NCH + b] = s + boutb;
            }
        }

        // ---- stage h_t into LDS (agent-scope loads bypass stale L1/L2) ----
        {
            float* src = hbuf + (size_t)(t & 1) * HID;
            #pragma unroll
            for (int k = 0; k < 4; ++k) {
                float v = __hip_atomic_load(src + tid + 512 * k,
                                            __ATOMIC_RELAXED, __HIP_MEMORY_SCOPE_AGENT);
                hs[tid + 512 * k] = v;
            }
        }
        __syncthreads();                                      // BAR B

        // ---- gates (critical path) ----
        if (t < TSTEPS) {
            float a0 = 0.f, a1 = 0.f, a2 = 0.f, a3 = 0.f;
            #pragma unroll
            for (int q = 0; q < 32; ++q) {
                const float hv = hs[lane + 64 * q];           // 2 lanes/bank: free
                a0 += wh[0][q] * hv; a1 += wh[1][q] * hv;
                a2 += wh[2][q] * hv; a3 += wh[3][q] * hv;
            }
            #pragma unroll
            for (int j = 0; j < 8; ++j) {
                const float xj = xv[j];
                a0 += wx[0][j] * xj; a1 += wx[1][j] * xj;
                a2 += wx[2][j] * xj; a3 += wx[3][j] * xj;
            }
            #pragma unroll
            for (int m = 32; m >= 1; m >>= 1) {               // butterfly: all lanes get sums
                a0 += __shfl_xor(a0, m, 64);
                a1 += __shfl_xor(a1, m, 64);
                a2 += __shfl_xor(a2, m, 64);
                a3 += __shfl_xor(a3, m, 64);
            }
            const float f = sig_(a0 + bias0);
            const float i = sig_(a1 + bias1);
            const float o = sig_(a2 + bias2);
            const float g = th_(a3 + bias3);
            c = f * c + i * g;                                // replicated across lanes
            const float hn = o * th_(c);
            if (lane == 0) {
                __hip_atomic_store(hbuf + (size_t)((t + 1) & 1) * HID + hidx, hn,
                                   __ATOMIC_RELAXED, __HIP_MEMORY_SCOPE_AGENT);
                if (t == TSTEPS - 1) {
                    dout[(size_t)TSTEPS * NCH + hidx]       = hn;   // h_last
                    dout[(size_t)TSTEPS * NCH + HID + hidx] = c;    // c_last
                }
            }
        }

        __syncthreads();     // BAR C: drains h stores (vmcnt(0)) before the arrival signal

        // ---- release as early as possible ----
        if (tid == 0 && t < TSTEPS) {
            // two-level arrival tree: 32 per group, then 8 groups -> global
            unsigned old = __hip_atomic_fetch_add(xcnt, 1u,
                               __ATOMIC_ACQ_REL, __HIP_MEMORY_SCOPE_AGENT);
            if (old == 32u * (unsigned)(t + 1) - 1u)
                __hip_atomic_fetch_add(gcnt, 1u,
                               __ATOMIC_ACQ_REL, __HIP_MEMORY_SCOPE_AGENT);
        }

        // ---- out[t-1] partials from staged h_t — AFTER arrival, overlaps others' spin.
        //      wpart consumed at next iteration after BAR A (or in epilogue).
        if (t > 0) {
            float op = 0.f;
            #pragma unroll
            for (int k = 0; k < 4; ++k) op += wrow[k] * hs[tid + 512 * k];
            #pragma unroll
            for (int m = 32; m >= 1; m >>= 1) op += __shfl_xor(op, m, 64);
            if (lane == 0) wpart[wave] = op;
        }
        ch = ch_next;
    }

    // epilogue: write out[TSTEPS-1] (partials from iteration t=TSTEPS)
    __syncthreads();
    if (tid == 0) {
        float s = wpart[0] + wpart[1] + wpart[2] + wpart[3]
                + wpart[4] + wpart[5] + wpart[6] + wpart[7];
        dout[(size_t)(TSTEPS - 1) * NCH + b] = s + boutb;
    }
}

extern "C" void kernel_launch(void* const* d_in, const int* in_sizes, int n_in,
                              void* d_out, int out_size, void* d_ws, size_t ws_size,
                              hipStream_t stream) {
    const int*   seq  = (const int*)d_in[0];
    const float* emb  = (const float*)d_in[1];
    const float* Wf   = (const float*)d_in[2];
    const float* bf   = (const float*)d_in[3];
    const float* Wi   = (const float*)d_in[4];
    const float* bi   = (const float*)d_in[5];
    const float* Wo   = (const float*)d_in[6];
    const float* bo   = (const float*)d_in[7];
    const float* Wc   = (const float*)d_in[8];
    const float* bc   = (const float*)d_in[9];
    const float* Wout = (const float*)d_in[10];
    const float* bout = (const float*)d_in[11];
    float*    dout = (float*)d_out;
    unsigned* cnt  = (unsigned*)d_ws;                       // 4 KB of counters
    float*    hbuf = (float*)((char*)d_ws + 4096);          // 2*2048 floats

    hipMemsetAsync(d_ws, 0, 4096 + 2 * HID * 4, stream);    // zero counters + h ping-pong
    hipLaunchKernelGGL(lstm_persist, dim3(NCU), dim3(TPB), 0, stream,
                       seq, emb, Wf, bf, Wi, bi, Wo, bo, Wc, bc, Wout, bout,
                       dout, cnt, hbuf);
}

// Round 3
// 9777.309 us; speedup vs baseline: 5.1557x; 5.1557x over previous
//
#include <hip/hip_runtime.h>

#define NCU     256
#define TPB     512      // 8 waves
#define HID     2048
#define EMBD    512
#define HIN     2560
#define TSTEPS  4096
#define NCH     256

typedef unsigned long long u64;

__device__ __forceinline__ float sig_(float x) { return 1.f / (1.f + __expf(-x)); }
__device__ __forceinline__ float th_(float x)  { float e = __expf(2.f * x); return 1.f - 2.f / (e + 1.f); }

__device__ __forceinline__ u64 ld_slot(const u64* p) {
    return __hip_atomic_load(p, __ATOMIC_RELAXED, __HIP_MEMORY_SCOPE_AGENT);
}

extern "C" __global__ void __launch_bounds__(TPB, 2)
lstm_persist(const int* __restrict__ seq,
             const float* __restrict__ emb,
             const float* __restrict__ Wf, const float* __restrict__ bf,
             const float* __restrict__ Wi, const float* __restrict__ bi,
             const float* __restrict__ Wo, const float* __restrict__ bo,
             const float* __restrict__ Wc, const float* __restrict__ bc,
             const float* __restrict__ Wout, const float* __restrict__ bout,
             float* __restrict__ dout,
             u64* __restrict__ hbuf)        // [2][2048] tagged ping-pong: hi32=step, lo32=float bits
{
    const int b    = blockIdx.x;          // CU id == output char id
    const int tid  = threadIdx.x;
    const int wave = tid >> 6;
    const int lane = tid & 63;
    const int hidx = b * 8 + wave;        // h index owned by this wave

    __shared__ float hs[HID];
    __shared__ float wpart[8];

    // ---- persistent weights in registers ----
    float wh[4][32];   // recurrent part: col = EMBD + lane + 64*q
    float wx[4][8];    // input part:     col = lane + 64*j
    {
        const float* Wm[4] = { Wf, Wi, Wo, Wc };
        #pragma unroll
        for (int g = 0; g < 4; ++g) {
            const float* row = Wm[g] + (size_t)hidx * HIN;
            #pragma unroll
            for (int q = 0; q < 32; ++q) wh[g][q] = row[EMBD + lane + 64 * q];
            #pragma unroll
            for (int j = 0; j < 8; ++j)  wx[g][j] = row[lane + 64 * j];
        }
    }
    float wrow[4];     // Wout row b, cols tid + 512*k
    #pragma unroll
    for (int k = 0; k < 4; ++k) wrow[k] = Wout[(size_t)b * HID + tid + 512 * k];

    // ---- defeat rematerialization: values become asm-defined, must stay in VGPRs ----
    #pragma unroll
    for (int g = 0; g < 4; ++g) {
        #pragma unroll
        for (int q = 0; q < 32; ++q) asm volatile("" : "+v"(wh[g][q]));
        #pragma unroll
        for (int j = 0; j < 8; ++j)  asm volatile("" : "+v"(wx[g][j]));
    }
    #pragma unroll
    for (int k = 0; k < 4; ++k) asm volatile("" : "+v"(wrow[k]));

    const float bias0 = bf[hidx], bias1 = bi[hidx], bias2 = bo[hidx], bias3 = bc[hidx];
    const float boutb = bout[b];

    float c = 0.f;
    int ch = seq[0];

    for (int t = 0; t <= TSTEPS; ++t) {
        // prefetch x for this step (independent of h, issued before the poll)
        float xv[8];
        if (t < TSTEPS) {
            const float* erow = emb + (size_t)ch * EMBD;
            #pragma unroll
            for (int j = 0; j < 8; ++j) xv[j] = erow[lane + 64 * j];
        }
        int ch_next = (t + 1 < TSTEPS) ? seq[t + 1] : 0;

        // ---- stage h_t into LDS: poll tagged slots (the store IS the arrival signal) ----
        if (t == 0) {
            #pragma unroll
            for (int k = 0; k < 4; ++k) hs[tid + 512 * k] = 0.f;
        } else {
            const u64* src = hbuf + (size_t)(t & 1) * HID;
            const u64* p0 = src + tid;
            const u64* p1 = src + tid + 512;
            const u64* p2 = src + tid + 1024;
            const u64* p3 = src + tid + 1536;
            const unsigned tt = (unsigned)t;
            u64 v0 = ld_slot(p0), v1 = ld_slot(p1), v2 = ld_slot(p2), v3 = ld_slot(p3);
            while (((unsigned)(v0 >> 32) != tt) | ((unsigned)(v1 >> 32) != tt) |
                   ((unsigned)(v2 >> 32) != tt) | ((unsigned)(v3 >> 32) != tt)) {
                __builtin_amdgcn_s_sleep(1);
                v0 = ld_slot(p0); v1 = ld_slot(p1); v2 = ld_slot(p2); v3 = ld_slot(p3);
            }
            hs[tid]        = __uint_as_float((unsigned)v0);
            hs[tid + 512]  = __uint_as_float((unsigned)v1);
            hs[tid + 1024] = __uint_as_float((unsigned)v2);
            hs[tid + 1536] = __uint_as_float((unsigned)v3);
        }
        __syncthreads();                                      // BAR B: hs ready

        // ---- gates (critical path) ----
        if (t < TSTEPS) {
            float a0 = 0.f, a1 = 0.f, a2 = 0.f, a3 = 0.f;
            #pragma unroll
            for (int q = 0; q < 32; ++q) {
                const float hv = hs[lane + 64 * q];           // 2 lanes/bank: free
                a0 += wh[0][q] * hv; a1 += wh[1][q] * hv;
                a2 += wh[2][q] * hv; a3 += wh[3][q] * hv;
            }
            #pragma unroll
            for (int j = 0; j < 8; ++j) {
                const float xj = xv[j];
                a0 += wx[0][j] * xj; a1 += wx[1][j] * xj;
                a2 += wx[2][j] * xj; a3 += wx[3][j] * xj;
            }
            #pragma unroll
            for (int m = 32; m >= 1; m >>= 1) {               // butterfly: all lanes get sums
                a0 += __shfl_xor(a0, m, 64);
                a1 += __shfl_xor(a1, m, 64);
                a2 += __shfl_xor(a2, m, 64);
                a3 += __shfl_xor(a3, m, 64);
            }
            const float f = sig_(a0 + bias0);
            const float i = sig_(a1 + bias1);
            const float o = sig_(a2 + bias2);
            const float g = th_(a3 + bias3);
            c = f * c + i * g;                                // replicated across lanes
            const float hn = o * th_(c);
            if (lane == 0) {
                const u64 pk = ((u64)(unsigned)(t + 1) << 32) | (u64)__float_as_uint(hn);
                __hip_atomic_store(hbuf + (size_t)((t + 1) & 1) * HID + hidx, pk,
                                   __ATOMIC_RELAXED, __HIP_MEMORY_SCOPE_AGENT);
                if (t == TSTEPS - 1) {
                    dout[(size_t)TSTEPS * NCH + hidx]       = hn;   // h_last
                    dout[(size_t)TSTEPS * NCH + HID + hidx] = c;    // c_last
                }
            }
        }

        // ---- out[t-1][b] from staged h_t — after the h release, overlaps others' polls ----
        if (t > 0) {
            float op = 0.f;
            #pragma unroll
            for (int k = 0; k < 4; ++k) op += wrow[k] * hs[tid + 512 * k];
            #pragma unroll
            for (int m = 32; m >= 1; m >>= 1) op += __shfl_xor(op, m, 64);
            if (lane == 0) wpart[wave] = op;
        }
        __syncthreads();                                      // BAR C: wpart ready, hs reusable

        if (tid == 0 && t > 0) {
            float s = wpart[0] + wpart[1] + wpart[2] + wpart[3]
                    + wpart[4] + wpart[5] + wpart[6] + wpart[7];
            dout[(size_t)(t - 1) * NCH + b] = s + boutb;
        }
        ch = ch_next;
    }
}

extern "C" void kernel_launch(void* const* d_in, const int* in_sizes, int n_in,
                              void* d_out, int out_size, void* d_ws, size_t ws_size,
                              hipStream_t stream) {
    const int*   seq  = (const int*)d_in[0];
    const float* emb  = (const float*)d_in[1];
    const float* Wf   = (const float*)d_in[2];
    const float* bf   = (const float*)d_in[3];
    const float* Wi   = (const float*)d_in[4];
    const float* bi   = (const float*)d_in[5];
    const float* Wo   = (const float*)d_in[6];
    const float* bo   = (const float*)d_in[7];
    const float* Wc   = (const float*)d_in[8];
    const float* bc   = (const float*)d_in[9];
    const float* Wout = (const float*)d_in[10];
    const float* bout = (const float*)d_in[11];
    float* dout = (float*)d_out;
    u64*   hbuf = (u64*)d_ws;                               // [2][2048] tagged slots

    hipMemsetAsync(d_ws, 0, 2 * HID * sizeof(u64), stream); // tags <- 0 (!= any wanted step >=1)
    hipLaunchKernelGGL(lstm_persist, dim3(NCU), dim3(TPB), 0, stream,
                       seq, emb, Wf, bf, Wi, bi, Wo, bo, Wc, bc, Wout, bout,
                       dout, hbuf);
}

// Round 4
// 9769.138 us; speedup vs baseline: 5.1601x; 1.0008x over previous
//
#include <hip/hip_runtime.h>

#define NCU     256
#define TPB     512      // 8 waves
#define HID     2048
#define EMBD    512
#define HIN     2560
#define TSTEPS  4096
#define NCH     256

typedef unsigned long long u64;
typedef float f32x32 __attribute__((ext_vector_type(32)));
typedef float f32x8  __attribute__((ext_vector_type(8)));
typedef float f32x4  __attribute__((ext_vector_type(4)));

__device__ __forceinline__ float sig_(float x) { return 1.f / (1.f + __expf(-x)); }
__device__ __forceinline__ float th_(float x)  { float e = __expf(2.f * x); return 1.f - 2.f / (e + 1.f); }

__device__ __forceinline__ u64 ld_slot(const u64* p) {
    return __hip_atomic_load(p, __ATOMIC_RELAXED, __HIP_MEMORY_SCOPE_AGENT);
}

extern "C" __global__ void __launch_bounds__(TPB, 2)
lstm_persist(const int* __restrict__ seq,
             const float* __restrict__ emb,
             const float* __restrict__ Wf, const float* __restrict__ bf,
             const float* __restrict__ Wi, const float* __restrict__ bi,
             const float* __restrict__ Wo, const float* __restrict__ bo,
             const float* __restrict__ Wc, const float* __restrict__ bc,
             const float* __restrict__ Wout, const float* __restrict__ bout,
             float* __restrict__ dout,
             u64* __restrict__ hbuf)        // [2][2048] tagged ping-pong: hi32=step, lo32=float bits
{
    const int b    = blockIdx.x;          // CU id == output char id
    const int tid  = threadIdx.x;
    const int wave = tid >> 6;
    const int lane = tid & 63;
    const int hidx = b * 8 + wave;        // h index owned by this wave

    __shared__ float hs[HID];
    __shared__ float wpart[8];

    // ---- persistent weights in named ext_vector registers (SSA values, no scratch) ----
    f32x32 wh0, wh1, wh2, wh3;            // recurrent: col = EMBD + lane + 64*q
    f32x8  wx0, wx1, wx2, wx3;            // input:     col = lane + 64*j
    f32x4  wrow;                          // Wout row b: col = tid + 512*k
    {
        const float* r0 = Wf + (size_t)hidx * HIN + EMBD;
        const float* r1 = Wi + (size_t)hidx * HIN + EMBD;
        const float* r2 = Wo + (size_t)hidx * HIN + EMBD;
        const float* r3 = Wc + (size_t)hidx * HIN + EMBD;
        #pragma unroll
        for (int q = 0; q < 32; ++q) {
            wh0[q] = r0[lane + 64 * q];
            wh1[q] = r1[lane + 64 * q];
            wh2[q] = r2[lane + 64 * q];
            wh3[q] = r3[lane + 64 * q];
        }
        const float* x0 = Wf + (size_t)hidx * HIN;
        const float* x1 = Wi + (size_t)hidx * HIN;
        const float* x2 = Wo + (size_t)hidx * HIN;
        const float* x3 = Wc + (size_t)hidx * HIN;
        #pragma unroll
        for (int j = 0; j < 8; ++j) {
            wx0[j] = x0[lane + 64 * j];
            wx1[j] = x1[lane + 64 * j];
            wx2[j] = x2[lane + 64 * j];
            wx3[j] = x3[lane + 64 * j];
        }
        #pragma unroll
        for (int k = 0; k < 4; ++k) wrow[k] = Wout[(size_t)b * HID + tid + 512 * k];
    }
    const float bias0 = bf[hidx], bias1 = bi[hidx], bias2 = bo[hidx], bias3 = bc[hidx];
    const float boutb = bout[b];

    float c = 0.f;
    int ch = seq[0];

    for (int t = 0; t <= TSTEPS; ++t) {
        // ---- x-contribution FIRST (depends only on prefetched ch, off the h critical path)
        float a0 = bias0, a1 = bias1, a2 = bias2, a3 = bias3;
        if (t < TSTEPS) {
            const float* erow = emb + (size_t)ch * EMBD;
            float xv[8];
            #pragma unroll
            for (int j = 0; j < 8; ++j) xv[j] = erow[lane + 64 * j];
            #pragma unroll
            for (int j = 0; j < 8; ++j) {
                const float xj = xv[j];
                a0 += wx0[j] * xj; a1 += wx1[j] * xj;
                a2 += wx2[j] * xj; a3 += wx3[j] * xj;
            }
        }
        int ch_next = (t + 1 < TSTEPS) ? seq[t + 1] : 0;

        // ---- stage h_t into LDS: poll tagged slots (the store IS the arrival signal) ----
        if (t == 0) {
            #pragma unroll
            for (int k = 0; k < 4; ++k) hs[tid + 512 * k] = 0.f;
        } else {
            const u64* src = hbuf + (size_t)(t & 1) * HID;
            const u64* p0 = src + tid;
            const u64* p1 = src + tid + 512;
            const u64* p2 = src + tid + 1024;
            const u64* p3 = src + tid + 1536;
            const unsigned tt = (unsigned)t;
            u64 v0 = ld_slot(p0), v1 = ld_slot(p1), v2 = ld_slot(p2), v3 = ld_slot(p3);
            while (((unsigned)(v0 >> 32) != tt) | ((unsigned)(v1 >> 32) != tt) |
                   ((unsigned)(v2 >> 32) != tt) | ((unsigned)(v3 >> 32) != tt)) {
                __builtin_amdgcn_s_sleep(1);
                v0 = ld_slot(p0); v1 = ld_slot(p1); v2 = ld_slot(p2); v3 = ld_slot(p3);
            }
            hs[tid]        = __uint_as_float((unsigned)v0);
            hs[tid + 512]  = __uint_as_float((unsigned)v1);
            hs[tid + 1024] = __uint_as_float((unsigned)v2);
            hs[tid + 1536] = __uint_as_float((unsigned)v3);
        }
        __syncthreads();                                      // BAR B: hs ready

        // ---- gates (critical path) ----
        if (t < TSTEPS) {
            #pragma unroll
            for (int q = 0; q < 32; ++q) {
                const float hv = hs[lane + 64 * q];           // 2 lanes/bank: free
                a0 += wh0[q] * hv; a1 += wh1[q] * hv;
                a2 += wh2[q] * hv; a3 += wh3[q] * hv;
            }
            #pragma unroll
            for (int m = 32; m >= 1; m >>= 1) {               // butterfly: all lanes get sums
                a0 += __shfl_xor(a0, m, 64);
                a1 += __shfl_xor(a1, m, 64);
                a2 += __shfl_xor(a2, m, 64);
                a3 += __shfl_xor(a3, m, 64);
            }
            const float f = sig_(a0);
            const float i = sig_(a1);
            const float o = sig_(a2);
            const float g = th_(a3);
            c = f * c + i * g;                                // replicated across lanes
            const float hn = o * th_(c);
            if (lane == 0) {
                const u64 pk = ((u64)(unsigned)(t + 1) << 32) | (u64)__float_as_uint(hn);
                __hip_atomic_store(hbuf + (size_t)((t + 1) & 1) * HID + hidx, pk,
                                   __ATOMIC_RELAXED, __HIP_MEMORY_SCOPE_AGENT);
                if (t == TSTEPS - 1) {
                    dout[(size_t)TSTEPS * NCH + hidx]       = hn;   // h_last
                    dout[(size_t)TSTEPS * NCH + HID + hidx] = c;    // c_last
                }
            }
        }

        // ---- out[t-1][b] from staged h_t — after the h release, overlaps others' polls ----
        if (t > 0) {
            float op = 0.f;
            #pragma unroll
            for (int k = 0; k < 4; ++k) op += wrow[k] * hs[tid + 512 * k];
            #pragma unroll
            for (int m = 32; m >= 1; m >>= 1) op += __shfl_xor(op, m, 64);
            if (lane == 0) wpart[wave] = op;
        }
        __syncthreads();                                      // BAR C: wpart ready, hs reusable

        if (tid == 0 && t > 0) {
            float s = wpart[0] + wpart[1] + wpart[2] + wpart[3]
                    + wpart[4] + wpart[5] + wpart[6] + wpart[7];
            dout[(size_t)(t - 1) * NCH + b] = s + boutb;
        }
        ch = ch_next;
    }
}

extern "C" void kernel_launch(void* const* d_in, const int* in_sizes, int n_in,
                              void* d_out, int out_size, void* d_ws, size_t ws_size,
                              hipStream_t stream) {
    const int*   seq  = (const int*)d_in[0];
    const float* emb  = (const float*)d_in[1];
    const float* Wf   = (const float*)d_in[2];
    const float* bf   = (const float*)d_in[3];
    const float* Wi   = (const float*)d_in[4];
    const float* bi   = (const float*)d_in[5];
    const float* Wo   = (const float*)d_in[6];
    const float* bo   = (const float*)d_in[7];
    const float* Wc   = (const float*)d_in[8];
    const float* bc   = (const float*)d_in[9];
    const float* Wout = (const float*)d_in[10];
    const float* bout = (const float*)d_in[11];
    float* dout = (float*)d_out;
    u64*   hbuf = (u64*)d_ws;                               // [2][2048] tagged slots

    hipMemsetAsync(d_ws, 0, 2 * HID * sizeof(u64), stream); // tags <- 0 (!= any wanted step >=1)
    hipLaunchKernelGGL(lstm_persist, dim3(NCU), dim3(TPB), 0, stream,
                       seq, emb, Wf, bf, Wi, bi, Wo, bo, Wc, bc, Wout, bout,
                       dout, hbuf);
}